// Round 2
// baseline (1277.651 us; speedup 1.0000x reference)
//
#include <hip/hip_runtime.h>
#include <math.h>

#define NN 50000
#define NE 800000
#define TT 6
#define HID 48

__device__ __forceinline__ float sigmoidf_(float x){ return 1.0f/(1.0f+__expf(-x)); }
__device__ __forceinline__ unsigned f2bf(float x){
  unsigned u = __float_as_uint(x);
  return (u + 0x7fffu + ((u>>16)&1u)) >> 16;   // RNE to bf16
}
__device__ __forceinline__ unsigned pack2(float a, float b){
  return f2bf(a) | (f2bf(b)<<16);
}
__device__ __forceinline__ float bflo(unsigned u){ return __uint_as_float(u<<16); }
__device__ __forceinline__ float bfhi(unsigned u){ return __uint_as_float(u & 0xffff0000u); }

// ---------------- setup ----------------
__global__ __launch_bounds__(256) void k_setup(float* deg, int* cnt,
                                               const float* __restrict__ Wih, const float* __restrict__ Whh,
                                               float* WihT, float* WhhT){
  int i = blockIdx.x*256+threadIdx.x;
  if(i<NN){ deg[i]=1.0f; cnt[i]=0; }          // self-loop weight 1 pre-added
  if(i<144*HID){ int o=i/HID, k=i%HID; WihT[k*144+o]=Wih[i]; WhhT[k*144+o]=Whh[i]; }
}

__global__ __launch_bounds__(256) void k_degcnt(const int* __restrict__ ei, const float* __restrict__ ew,
                                                float* deg, int* cnt){
  int e = blockIdx.x*256+threadIdx.x;
  if(e<NE){
    int c = ei[NE+e];
    atomicAdd(&deg[c], ew[e]);
    atomicAdd(&cnt[c], 1);
  }
}

// prefix sum of cnt -> offs/cursor, plus dis = rsqrt(deg)
__global__ __launch_bounds__(1024) void k_scan(const int* __restrict__ cnt, const float* __restrict__ deg,
                                               int* offs, int* cursor, float* dis){
  __shared__ int part[1024];
  int tid=threadIdx.x;
  const int CH=(NN+1023)/1024; // 49
  int lo=tid*CH, hi=lo+CH; if(hi>NN) hi=NN; if(lo>NN) lo=NN;
  int s=0;
  for(int i=lo;i<hi;i++){
    s+=cnt[i];
    float d=deg[i];
    dis[i] = d>0.f ? rsqrtf(fmaxf(d,1e-12f)) : 0.f;
  }
  part[tid]=s;
  __syncthreads();
  for(int off=1;off<1024;off<<=1){
    int v = (tid>=off)? part[tid-off] : 0;
    __syncthreads();
    part[tid]+=v;
    __syncthreads();
  }
  int run = (tid==0)?0:part[tid-1];
  for(int i=lo;i<hi;i++){ offs[i]=run; cursor[i]=run; run+=cnt[i]; }
  if(tid==1023) offs[NN]=part[1023];
}

__global__ __launch_bounds__(256) void k_scatter(const int* __restrict__ ei, const float* __restrict__ ew,
                                                 const float* __restrict__ dis, int* cursor,
                                                 int2* __restrict__ csr){
  int e = blockIdx.x*256+threadIdx.x;
  if(e<NE){
    int r=ei[e], c=ei[NE+e];
    int pos=atomicAdd(&cursor[c],1);
    int2 v; v.x=r; v.y=__float_as_int(dis[r]*ew[e]*dis[c]);
    csr[pos]=v;
  }
}

// ---------------- layer-0 matmul, all 6 t per thread, bf16 [f][t8] output ----------------
// thread = (node n, feature-slice s of 12). A row per node = 48 uint4 (768B): offset f*16 + t*2 bytes.
__global__ __launch_bounds__(256) void k_mm0(const float* __restrict__ X, const float* __restrict__ W,
                                             uint4* __restrict__ A){
  int tid = blockIdx.x*256+threadIdx.x;
  int n = tid>>2, s = tid&3;
  if(n>=NN) return;
  const float* xb = X + (long long)n*64;
  const float* wb = W + 12*s;
  float acc[TT][12];
#pragma unroll
  for(int t=0;t<TT;t++)
#pragma unroll
    for(int j=0;j<12;j++) acc[t][j]=0.f;
#pragma unroll 2
  for(int k4=0;k4<16;k4++){
    float4 xv[TT];
#pragma unroll
    for(int t=0;t<TT;t++) xv[t] = *reinterpret_cast<const float4*>(xb + (long long)t*NN*64 + 4*k4);
#pragma unroll
    for(int q=0;q<4;q++){
      const float* wr = wb + (4*k4+q)*HID;
      float w[12];
#pragma unroll
      for(int j=0;j<12;j++) w[j]=wr[j];
#pragma unroll
      for(int t=0;t<TT;t++){
        float xs = (&xv[t].x)[q];
#pragma unroll
        for(int j=0;j<12;j++) acc[t][j] = fmaf(xs, w[j], acc[t][j]);
      }
    }
  }
  uint4* out = A + (long long)n*48 + 12*s;
#pragma unroll
  for(int j=0;j<12;j++){
    uint4 v;
    v.x=pack2(acc[0][j],acc[1][j]);
    v.y=pack2(acc[2][j],acc[3][j]);
    v.z=pack2(acc[4][j],acc[5][j]);
    v.w=0u;
    out[j]=v;
  }
}

// ---------------- layer-1 matmul (K=48), input fp32 [n][t][48] ----------------
__global__ __launch_bounds__(256) void k_mm1(const float* __restrict__ X, const float* __restrict__ W,
                                             uint4* __restrict__ A){
  int tid = blockIdx.x*256+threadIdx.x;
  int n = tid>>2, s = tid&3;
  if(n>=NN) return;
  const float* xb = X + (long long)n*(TT*HID);
  const float* wb = W + 12*s;
  float acc[TT][12];
#pragma unroll
  for(int t=0;t<TT;t++)
#pragma unroll
    for(int j=0;j<12;j++) acc[t][j]=0.f;
#pragma unroll 2
  for(int k4=0;k4<12;k4++){
    float4 xv[TT];
#pragma unroll
    for(int t=0;t<TT;t++) xv[t] = *reinterpret_cast<const float4*>(xb + t*HID + 4*k4);
#pragma unroll
    for(int q=0;q<4;q++){
      const float* wr = wb + (4*k4+q)*HID;
      float w[12];
#pragma unroll
      for(int j=0;j<12;j++) w[j]=wr[j];
#pragma unroll
      for(int t=0;t<TT;t++){
        float xs = (&xv[t].x)[q];
#pragma unroll
        for(int j=0;j<12;j++) acc[t][j] = fmaf(xs, w[j], acc[t][j]);
      }
    }
  }
  uint4* out = A + (long long)n*48 + 12*s;
#pragma unroll
  for(int j=0;j<12;j++){
    uint4 v;
    v.x=pack2(acc[0][j],acc[1][j]);
    v.y=pack2(acc[2][j],acc[3][j]);
    v.z=pack2(acc[4][j],acc[5][j]);
    v.w=0u;
    out[j]=v;
  }
}

// ---------------- CSR aggregation (bf16 gather) + bias + LN + ReLU (+resid), fp32 out [n][t][48]
__global__ __launch_bounds__(256) void k_agg(const uint4* __restrict__ A, const float* __restrict__ bias,
                                             const float* __restrict__ gain, const float* __restrict__ beta,
                                             const float* __restrict__ resid, float* __restrict__ out,
                                             const int* __restrict__ offs, const int2* __restrict__ csr,
                                             const float* __restrict__ dis){
  int wid = (blockIdx.x*256+threadIdx.x)>>6;
  int lane = threadIdx.x & 63;
  if(wid>=NN) return;
  const bool act = lane<HID;
  const int f = act? lane : (HID-1);
  float dn = dis[wid];
  float sw = dn*dn;
  float acc[TT];
  {
    uint4 v = A[(long long)wid*48 + f];
    acc[0]=sw*bflo(v.x); acc[1]=sw*bfhi(v.x);
    acc[2]=sw*bflo(v.y); acc[3]=sw*bfhi(v.y);
    acc[4]=sw*bflo(v.z); acc[5]=sw*bfhi(v.z);
  }
  int e0=offs[wid], e1=offs[wid+1];
  int e=e0;
  for(; e+1<e1; e+=2){
    int2 i0=csr[e], i1=csr[e+1];
    uint4 d0 = A[(long long)i0.x*48 + f];
    uint4 d1 = A[(long long)i1.x*48 + f];
    float n0=__int_as_float(i0.y), n1=__int_as_float(i1.y);
    acc[0]=fmaf(n0,bflo(d0.x),acc[0]); acc[1]=fmaf(n0,bfhi(d0.x),acc[1]);
    acc[2]=fmaf(n0,bflo(d0.y),acc[2]); acc[3]=fmaf(n0,bfhi(d0.y),acc[3]);
    acc[4]=fmaf(n0,bflo(d0.z),acc[4]); acc[5]=fmaf(n0,bfhi(d0.z),acc[5]);
    acc[0]=fmaf(n1,bflo(d1.x),acc[0]); acc[1]=fmaf(n1,bfhi(d1.x),acc[1]);
    acc[2]=fmaf(n1,bflo(d1.y),acc[2]); acc[3]=fmaf(n1,bfhi(d1.y),acc[3]);
    acc[4]=fmaf(n1,bflo(d1.z),acc[4]); acc[5]=fmaf(n1,bfhi(d1.z),acc[5]);
  }
  if(e<e1){
    int2 i0=csr[e];
    uint4 d0 = A[(long long)i0.x*48 + f];
    float n0=__int_as_float(i0.y);
    acc[0]=fmaf(n0,bflo(d0.x),acc[0]); acc[1]=fmaf(n0,bfhi(d0.x),acc[1]);
    acc[2]=fmaf(n0,bflo(d0.y),acc[2]); acc[3]=fmaf(n0,bfhi(d0.y),acc[3]);
    acc[4]=fmaf(n0,bflo(d0.z),acc[4]); acc[5]=fmaf(n0,bfhi(d0.z),acc[5]);
  }
  float bb = bias[f], gg = gain[f], be = beta[f];
  const float rn = 1.0f/HID;
#pragma unroll
  for(int t=0;t<TT;t++){
    float val = acc[t] + bb;
    float v = act? val : 0.f;
    float s = v, s2 = v*v;
#pragma unroll
    for(int m=32;m>=1;m>>=1){
      s  += __shfl_xor(s,  m, 64);
      s2 += __shfl_xor(s2, m, 64);
    }
    float mu  = s*rn;
    float var = fmaxf(s2*rn - mu*mu, 0.f);
    float y = (val-mu)*rsqrtf(var+1e-5f)*gg + be;
    y = fmaxf(y, 0.f);
    long long oidx = (long long)wid*(TT*HID) + t*HID + f;
    if(resid) y += resid[oidx];
    if(act) out[oidx] = y;
  }
}

// ---------------- GRU step: 3 threads per node (16 features each), ping-pong hidden ----------------
__global__ __launch_bounds__(256) void k_gru(const float* __restrict__ X, long long xstride,
                                             const float* __restrict__ WihT, const float* __restrict__ WhhT,
                                             const float* __restrict__ bih, const float* __restrict__ bhh,
                                             const float* __restrict__ hin, float* __restrict__ hout){
  int n = blockIdx.x*blockDim.x+threadIdx.x;
  if(n>=NN) return;
  int f0 = blockIdx.y*16;
  const float* xr = X + (long long)n*xstride;
  const float* hr = hin + (long long)n*HID;
  float ra[16], za[16], ia[16], ha[16];
#pragma unroll
  for(int j=0;j<16;j++){ ra[j]=0.f; za[j]=0.f; ia[j]=0.f; ha[j]=0.f; }
  for(int k4=0;k4<HID/4;k4++){
    float4 xv = *reinterpret_cast<const float4*>(xr+4*k4);
    float4 hv = *reinterpret_cast<const float4*>(hr+4*k4);
    const float xs[4]={xv.x,xv.y,xv.z,xv.w};
    const float hs[4]={hv.x,hv.y,hv.z,hv.w};
#pragma unroll
    for(int q=0;q<4;q++){
      const float* wi = WihT + (4*k4+q)*144 + f0;
      const float* wh = WhhT + (4*k4+q)*144 + f0;
#pragma unroll
      for(int j=0;j<16;j++){
        ra[j] = fmaf(xs[q], wi[j],    ra[j]);
        ra[j] = fmaf(hs[q], wh[j],    ra[j]);
        za[j] = fmaf(xs[q], wi[48+j], za[j]);
        za[j] = fmaf(hs[q], wh[48+j], za[j]);
        ia[j] = fmaf(xs[q], wi[96+j], ia[j]);
        ha[j] = fmaf(hs[q], wh[96+j], ha[j]);
      }
    }
  }
#pragma unroll
  for(int j=0;j<16;j++){
    int f=f0+j;
    float r  = sigmoidf_(ra[j]+bih[f]+bhh[f]);
    float ng = tanhf(ia[j]+bih[96+f] + r*(ha[j]+bhh[96+f]));
    float zg = sigmoidf_(za[j]+bih[48+f]+bhh[48+f]);
    float hnew = (1.f-zg)*ng + zg*hr[f];
    hout[(long long)n*HID + f] = hnew;
  }
}

// ---------------- classifier head ----------------
__global__ __launch_bounds__(256) void k_cls(const float* __restrict__ z, const float* __restrict__ Wc1,
                                             const float* __restrict__ bc1, const float* __restrict__ Wc2,
                                             const float* __restrict__ bc2, float* __restrict__ out){
  int n = blockIdx.x*blockDim.x+threadIdx.x;
  if(n>=NN) return;
  const float* zr = z + (long long)n*HID;
  float hv[24];
#pragma unroll
  for(int j=0;j<24;j++) hv[j]=bc1[j];
  for(int k4=0;k4<HID/4;k4++){
    float4 zv = *reinterpret_cast<const float4*>(zr+4*k4);
    const float zs[4]={zv.x,zv.y,zv.z,zv.w};
#pragma unroll
    for(int q=0;q<4;q++){
      const float* wr = Wc1 + (4*k4+q)*24;
#pragma unroll
      for(int j=0;j<24;j++) hv[j] = fmaf(zs[q], wr[j], hv[j]);
    }
  }
  float l0=bc2[0], l1=bc2[1];
#pragma unroll
  for(int j=0;j<24;j++){
    float a = fmaxf(hv[j],0.f);
    l0 = fmaf(a, Wc2[2*j],   l0);
    l1 = fmaf(a, Wc2[2*j+1], l1);
  }
  out[2LL*n]=l0; out[2LL*n+1]=l1;
}

static inline size_t al256(size_t x){ return (x+255)&~(size_t)255; }

extern "C" void kernel_launch(void* const* d_in, const int* in_sizes, int n_in,
                              void* d_out, int out_size, void* d_ws, size_t ws_size,
                              hipStream_t stream){
  const float* x_seq=(const float*)d_in[0];
  const int*   ei   =(const int*)d_in[1];
  const float* ew   =(const float*)d_in[2];
  const float* W0=(const float*)d_in[3];  const float* b0=(const float*)d_in[4];
  const float* g0=(const float*)d_in[5];  const float* be0=(const float*)d_in[6];
  const float* W1=(const float*)d_in[7];  const float* b1=(const float*)d_in[8];
  const float* g1=(const float*)d_in[9];  const float* be1=(const float*)d_in[10];
  const float* Wih=(const float*)d_in[11];const float* Whh=(const float*)d_in[12];
  const float* bih=(const float*)d_in[13];const float* bhh=(const float*)d_in[14];
  const float* Wc1=(const float*)d_in[15];const float* bc1=(const float*)d_in[16];
  const float* Wc2=(const float*)d_in[17];const float* bc2=(const float*)d_in[18];
  float* outp=(float*)d_out;

  char* p=(char*)d_ws; size_t off=0;
  auto alloc=[&](size_t bytes)->void*{ void* r=p+off; off=al256(off+bytes); return r; };
  float* deg    =(float*)alloc((size_t)NN*4);
  float* dis    =(float*)alloc((size_t)NN*4);
  int*   cnt    =(int*)  alloc((size_t)NN*4);
  int*   offs   =(int*)  alloc((size_t)(NN+1)*4);
  int*   cursor =(int*)  alloc((size_t)NN*4);
  int2*  csr    =(int2*) alloc((size_t)NE*8);
  float* WihT   =(float*)alloc((size_t)144*48*4);
  float* WhhT   =(float*)alloc((size_t)144*48*4);
  float* z0     =(float*)alloc((size_t)NN*HID*4);
  float* z1     =(float*)alloc((size_t)NN*HID*4);
  uint4* A      =(uint4*)alloc((size_t)NN*768 + 1024);      // bf16 [n][f][t8], 768B/row
  float* h1     =(float*)alloc((size_t)NN*TT*HID*4);
  float* h2     =(float*)alloc((size_t)NN*TT*HID*4);

  const int GN=(NN+255)/256, GE=(NE+255)/256;
  const int GMM=(NN*4+255)/256;          // 4 threads/node
  const int GAGG=(NN*64+255)/256;        // 1 wave/node

  k_setup  <<<GN,256,0,stream>>>(deg,cnt,Wih,Whh,WihT,WhhT);
  k_degcnt <<<GE,256,0,stream>>>(ei,ew,deg,cnt);
  k_scan   <<<1,1024,0,stream>>>(cnt,deg,offs,cursor,dis);
  k_scatter<<<GE,256,0,stream>>>(ei,ew,dis,cursor,csr);
  hipMemsetAsync(z0,0,(size_t)NN*HID*4,stream);

  // layer 0
  k_mm0<<<GMM,256,0,stream>>>(x_seq, W0, A);
  k_agg<<<GAGG,256,0,stream>>>(A,b0,g0,be0,nullptr,h1,offs,csr,dis);
  // layer 1 (residual = h1)
  k_mm1<<<GMM,256,0,stream>>>(h1, W1, A);
  k_agg<<<GAGG,256,0,stream>>>(A,b1,g1,be1,h1,h2,offs,csr,dis);
  // GRU over time
  for(int t=0;t<TT;t++){
    const float* hin=(t&1)? z1:z0;
    float* hout=(t&1)? z0:z1;
    k_gru<<<dim3(GN,3),256,0,stream>>>(h2+(long long)t*HID, (long long)TT*HID, WihT,WhhT,bih,bhh,hin,hout);
  }
  // after t=5 (odd), final hidden is in z0
  k_cls<<<GN,256,0,stream>>>(z0,Wc1,bc1,Wc2,bc2,outp);
}

// Round 3
// 1025.138 us; speedup vs baseline: 1.2463x; 1.2463x over previous
//
#include <hip/hip_runtime.h>
#include <math.h>

#define NN 50000
#define NE 800000
#define TT 6
#define HID 48
#define NB 196   // (NN+255)/256

__device__ __forceinline__ float sigmoidf_(float x){ return 1.0f/(1.0f+__expf(-x)); }
__device__ __forceinline__ unsigned f2bf(float x){
  unsigned u = __float_as_uint(x);
  return (u + 0x7fffu + ((u>>16)&1u)) >> 16;   // RNE to bf16
}
__device__ __forceinline__ unsigned pack2(float a, float b){
  return f2bf(a) | (f2bf(b)<<16);
}
__device__ __forceinline__ float bflo(unsigned u){ return __uint_as_float(u<<16); }
__device__ __forceinline__ float bfhi(unsigned u){ return __uint_as_float(u & 0xffff0000u); }

struct U3 { unsigned x,y,z; };

// 256-thread inclusive block scan (4 waves of 64)
__device__ __forceinline__ int block_scan_incl(int x, int* wsum){
  int lane = threadIdx.x & 63, w = threadIdx.x >> 6;
  int v = x;
#pragma unroll
  for(int d=1; d<64; d<<=1){
    int u = __shfl_up(v, d, 64);
    if(lane >= d) v += u;
  }
  if(lane==63) wsum[w] = v;
  __syncthreads();
  int add = 0;
#pragma unroll
  for(int k=0;k<3;k++) if(w>k) add += wsum[k];
  return v + add;
}

// ---------------- setup ----------------
__global__ __launch_bounds__(256) void k_setup(float* deg, int* cnt,
                                               const float* __restrict__ Wih, const float* __restrict__ Whh,
                                               float* WihT, float* WhhT){
  int i = blockIdx.x*256+threadIdx.x;
  if(i<NN){ deg[i]=1.0f; cnt[i]=0; }          // self-loop weight 1 pre-added
  if(i<144*HID){ int o=i/HID, k=i%HID; WihT[k*144+o]=Wih[i]; WhhT[k*144+o]=Whh[i]; }
}

__global__ __launch_bounds__(256) void k_degcnt(const int* __restrict__ ei, const float* __restrict__ ew,
                                                float* deg, int* cnt){
  int e = blockIdx.x*256+threadIdx.x;
  if(e<NE){
    int c = ei[NE+e];
    atomicAdd(&deg[c], ew[e]);
    atomicAdd(&cnt[c], 1);
  }
}

// phase A: per-block sums of cnt, plus dis = rsqrt(deg)
__global__ __launch_bounds__(256) void k_partA(const int* __restrict__ cnt, const float* __restrict__ deg,
                                               float* dis, int* bsum){
  __shared__ int wsum[4];
  int i = blockIdx.x*256+threadIdx.x;
  int x = 0;
  if(i<NN){
    x = cnt[i];
    float d = deg[i];
    dis[i] = d>0.f ? rsqrtf(fmaxf(d,1e-12f)) : 0.f;
  }
  int lane = threadIdx.x & 63, w = threadIdx.x >> 6;
  int v = x;
#pragma unroll
  for(int m=32;m>=1;m>>=1) v += __shfl_xor(v, m, 64);
  if(lane==0) wsum[w]=v;
  __syncthreads();
  if(threadIdx.x==0) bsum[blockIdx.x] = wsum[0]+wsum[1]+wsum[2]+wsum[3];
}

// phase B: exclusive scan of 196 block sums
__global__ __launch_bounds__(256) void k_midB(const int* __restrict__ bsum, int* bpre, int* offs){
  __shared__ int wsum[4];
  int t = threadIdx.x;
  int x = (t<NB)? bsum[t] : 0;
  int incl = block_scan_incl(x, wsum);
  if(t<NB) bpre[t] = incl - x;
  if(t==255) offs[NN] = incl;   // total
}

// phase C: per-block exclusive scan of cnt + bpre -> offs/cursor
__global__ __launch_bounds__(256) void k_offsC(const int* __restrict__ cnt, const int* __restrict__ bpre,
                                               int* offs, int* cursor){
  __shared__ int wsum[4];
  int i = blockIdx.x*256+threadIdx.x;
  int x = (i<NN)? cnt[i] : 0;
  int incl = block_scan_incl(x, wsum);
  int val = bpre[blockIdx.x] + incl - x;
  if(i<NN){ offs[i]=val; cursor[i]=val; }
}

__global__ __launch_bounds__(256) void k_scatter(const int* __restrict__ ei, const float* __restrict__ ew,
                                                 const float* __restrict__ dis, int* cursor,
                                                 int2* __restrict__ csr){
  int e = blockIdx.x*256+threadIdx.x;
  if(e<NE){
    int r=ei[e], c=ei[NE+e];
    int pos=atomicAdd(&cursor[c],1);
    int2 v; v.x=r; v.y=__float_as_int(dis[r]*ew[e]*dis[c]);
    csr[pos]=v;
  }
}

// ---------------- layer-0 matmul, all 6 t per thread, bf16 [f][t6] 12B/feature output ----------------
// A row per node = 144 words (576B): feature f at word offset f*3.
__global__ __launch_bounds__(256) void k_mm0(const float* __restrict__ X, const float* __restrict__ W,
                                             unsigned* __restrict__ A){
  int tid = blockIdx.x*256+threadIdx.x;
  int n = tid>>2, s = tid&3;
  if(n>=NN) return;
  const float* xb = X + (long long)n*64;
  const float* wb = W + 12*s;
  float acc[TT][12];
#pragma unroll
  for(int t=0;t<TT;t++)
#pragma unroll
    for(int j=0;j<12;j++) acc[t][j]=0.f;
#pragma unroll 2
  for(int k4=0;k4<16;k4++){
    float4 xv[TT];
#pragma unroll
    for(int t=0;t<TT;t++) xv[t] = *reinterpret_cast<const float4*>(xb + (long long)t*NN*64 + 4*k4);
#pragma unroll
    for(int q=0;q<4;q++){
      const float* wr = wb + (4*k4+q)*HID;
      float w[12];
#pragma unroll
      for(int j=0;j<12;j++) w[j]=wr[j];
#pragma unroll
      for(int t=0;t<TT;t++){
        float xs = (&xv[t].x)[q];
#pragma unroll
        for(int j=0;j<12;j++) acc[t][j] = fmaf(xs, w[j], acc[t][j]);
      }
    }
  }
  unsigned buf[36];
#pragma unroll
  for(int j=0;j<12;j++){
    buf[3*j  ]=pack2(acc[0][j],acc[1][j]);
    buf[3*j+1]=pack2(acc[2][j],acc[3][j]);
    buf[3*j+2]=pack2(acc[4][j],acc[5][j]);
  }
  uint4* o4 = reinterpret_cast<uint4*>(A + (long long)n*144 + 36*s);
#pragma unroll
  for(int q=0;q<9;q++) o4[q] = make_uint4(buf[4*q],buf[4*q+1],buf[4*q+2],buf[4*q+3]);
}

// ---------------- layer-1 matmul (K=48), input fp32 [n][t][48] ----------------
__global__ __launch_bounds__(256) void k_mm1(const float* __restrict__ X, const float* __restrict__ W,
                                             unsigned* __restrict__ A){
  int tid = blockIdx.x*256+threadIdx.x;
  int n = tid>>2, s = tid&3;
  if(n>=NN) return;
  const float* xb = X + (long long)n*(TT*HID);
  const float* wb = W + 12*s;
  float acc[TT][12];
#pragma unroll
  for(int t=0;t<TT;t++)
#pragma unroll
    for(int j=0;j<12;j++) acc[t][j]=0.f;
#pragma unroll 2
  for(int k4=0;k4<12;k4++){
    float4 xv[TT];
#pragma unroll
    for(int t=0;t<TT;t++) xv[t] = *reinterpret_cast<const float4*>(xb + t*HID + 4*k4);
#pragma unroll
    for(int q=0;q<4;q++){
      const float* wr = wb + (4*k4+q)*HID;
      float w[12];
#pragma unroll
      for(int j=0;j<12;j++) w[j]=wr[j];
#pragma unroll
      for(int t=0;t<TT;t++){
        float xs = (&xv[t].x)[q];
#pragma unroll
        for(int j=0;j<12;j++) acc[t][j] = fmaf(xs, w[j], acc[t][j]);
      }
    }
  }
  unsigned buf[36];
#pragma unroll
  for(int j=0;j<12;j++){
    buf[3*j  ]=pack2(acc[0][j],acc[1][j]);
    buf[3*j+1]=pack2(acc[2][j],acc[3][j]);
    buf[3*j+2]=pack2(acc[4][j],acc[5][j]);
  }
  uint4* o4 = reinterpret_cast<uint4*>(A + (long long)n*144 + 36*s);
#pragma unroll
  for(int q=0;q<9;q++) o4[q] = make_uint4(buf[4*q],buf[4*q+1],buf[4*q+2],buf[4*q+3]);
}

// ---------------- CSR aggregation (bf16 gather, 12B/edge-feature) + bias + LN + ReLU (+resid)
__global__ __launch_bounds__(256) void k_agg(const unsigned* __restrict__ A, const float* __restrict__ bias,
                                             const float* __restrict__ gain, const float* __restrict__ beta,
                                             const float* __restrict__ resid, float* __restrict__ out,
                                             const int* __restrict__ offs, const int2* __restrict__ csr,
                                             const float* __restrict__ dis){
  int wid = (blockIdx.x*256+threadIdx.x)>>6;
  int lane = threadIdx.x & 63;
  if(wid>=NN) return;
  const bool act = lane<HID;
  const int f = act? lane : (HID-1);
  float dn = dis[wid];
  float sw = dn*dn;
  float acc[TT];
  {
    U3 v = *reinterpret_cast<const U3*>(A + (long long)wid*144 + 3*f);
    acc[0]=sw*bflo(v.x); acc[1]=sw*bfhi(v.x);
    acc[2]=sw*bflo(v.y); acc[3]=sw*bfhi(v.y);
    acc[4]=sw*bflo(v.z); acc[5]=sw*bfhi(v.z);
  }
  int e0=offs[wid], e1=offs[wid+1];
  int e=e0;
  for(; e+1<e1; e+=2){
    int2 i0=csr[e], i1=csr[e+1];
    U3 d0 = *reinterpret_cast<const U3*>(A + (long long)i0.x*144 + 3*f);
    U3 d1 = *reinterpret_cast<const U3*>(A + (long long)i1.x*144 + 3*f);
    float n0=__int_as_float(i0.y), n1=__int_as_float(i1.y);
    acc[0]=fmaf(n0,bflo(d0.x),acc[0]); acc[1]=fmaf(n0,bfhi(d0.x),acc[1]);
    acc[2]=fmaf(n0,bflo(d0.y),acc[2]); acc[3]=fmaf(n0,bfhi(d0.y),acc[3]);
    acc[4]=fmaf(n0,bflo(d0.z),acc[4]); acc[5]=fmaf(n0,bfhi(d0.z),acc[5]);
    acc[0]=fmaf(n1,bflo(d1.x),acc[0]); acc[1]=fmaf(n1,bfhi(d1.x),acc[1]);
    acc[2]=fmaf(n1,bflo(d1.y),acc[2]); acc[3]=fmaf(n1,bfhi(d1.y),acc[3]);
    acc[4]=fmaf(n1,bflo(d1.z),acc[4]); acc[5]=fmaf(n1,bfhi(d1.z),acc[5]);
  }
  if(e<e1){
    int2 i0=csr[e];
    U3 d0 = *reinterpret_cast<const U3*>(A + (long long)i0.x*144 + 3*f);
    float n0=__int_as_float(i0.y);
    acc[0]=fmaf(n0,bflo(d0.x),acc[0]); acc[1]=fmaf(n0,bfhi(d0.x),acc[1]);
    acc[2]=fmaf(n0,bflo(d0.y),acc[2]); acc[3]=fmaf(n0,bfhi(d0.y),acc[3]);
    acc[4]=fmaf(n0,bflo(d0.z),acc[4]); acc[5]=fmaf(n0,bfhi(d0.z),acc[5]);
  }
  float bb = bias[f], gg = gain[f], be = beta[f];
  const float rn = 1.0f/HID;
#pragma unroll
  for(int t=0;t<TT;t++){
    float val = acc[t] + bb;
    float v = act? val : 0.f;
    float s = v, s2 = v*v;
#pragma unroll
    for(int m=32;m>=1;m>>=1){
      s  += __shfl_xor(s,  m, 64);
      s2 += __shfl_xor(s2, m, 64);
    }
    float mu  = s*rn;
    float var = fmaxf(s2*rn - mu*mu, 0.f);
    float y = (val-mu)*rsqrtf(var+1e-5f)*gg + be;
    y = fmaxf(y, 0.f);
    long long oidx = (long long)wid*(TT*HID) + t*HID + f;
    if(resid) y += resid[oidx];
    if(act) out[oidx] = y;
  }
}

// ---------------- GRU step: 3 threads per node (16 features each), ping-pong hidden ----------------
__global__ __launch_bounds__(256) void k_gru(const float* __restrict__ X, long long xstride,
                                             const float* __restrict__ WihT, const float* __restrict__ WhhT,
                                             const float* __restrict__ bih, const float* __restrict__ bhh,
                                             const float* __restrict__ hin, float* __restrict__ hout){
  int n = blockIdx.x*blockDim.x+threadIdx.x;
  if(n>=NN) return;
  int f0 = blockIdx.y*16;
  const float* xr = X + (long long)n*xstride;
  const float* hr = hin + (long long)n*HID;
  float ra[16], za[16], ia[16], ha[16];
#pragma unroll
  for(int j=0;j<16;j++){ ra[j]=0.f; za[j]=0.f; ia[j]=0.f; ha[j]=0.f; }
  for(int k4=0;k4<HID/4;k4++){
    float4 xv = *reinterpret_cast<const float4*>(xr+4*k4);
    float4 hv = *reinterpret_cast<const float4*>(hr+4*k4);
    const float xs[4]={xv.x,xv.y,xv.z,xv.w};
    const float hs[4]={hv.x,hv.y,hv.z,hv.w};
#pragma unroll
    for(int q=0;q<4;q++){
      const float* wi = WihT + (4*k4+q)*144 + f0;
      const float* wh = WhhT + (4*k4+q)*144 + f0;
#pragma unroll
      for(int j=0;j<16;j++){
        ra[j] = fmaf(xs[q], wi[j],    ra[j]);
        ra[j] = fmaf(hs[q], wh[j],    ra[j]);
        za[j] = fmaf(xs[q], wi[48+j], za[j]);
        za[j] = fmaf(hs[q], wh[48+j], za[j]);
        ia[j] = fmaf(xs[q], wi[96+j], ia[j]);
        ha[j] = fmaf(hs[q], wh[96+j], ha[j]);
      }
    }
  }
#pragma unroll
  for(int j=0;j<16;j++){
    int f=f0+j;
    float r  = sigmoidf_(ra[j]+bih[f]+bhh[f]);
    float ng = tanhf(ia[j]+bih[96+f] + r*(ha[j]+bhh[96+f]));
    float zg = sigmoidf_(za[j]+bih[48+f]+bhh[48+f]);
    float hnew = (1.f-zg)*ng + zg*hr[f];
    hout[(long long)n*HID + f] = hnew;
  }
}

// ---------------- classifier head ----------------
__global__ __launch_bounds__(256) void k_cls(const float* __restrict__ z, const float* __restrict__ Wc1,
                                             const float* __restrict__ bc1, const float* __restrict__ Wc2,
                                             const float* __restrict__ bc2, float* __restrict__ out){
  int n = blockIdx.x*blockDim.x+threadIdx.x;
  if(n>=NN) return;
  const float* zr = z + (long long)n*HID;
  float hv[24];
#pragma unroll
  for(int j=0;j<24;j++) hv[j]=bc1[j];
  for(int k4=0;k4<HID/4;k4++){
    float4 zv = *reinterpret_cast<const float4*>(zr+4*k4);
    const float zs[4]={zv.x,zv.y,zv.z,zv.w};
#pragma unroll
    for(int q=0;q<4;q++){
      const float* wr = Wc1 + (4*k4+q)*24;
#pragma unroll
      for(int j=0;j<24;j++) hv[j] = fmaf(zs[q], wr[j], hv[j]);
    }
  }
  float l0=bc2[0], l1=bc2[1];
#pragma unroll
  for(int j=0;j<24;j++){
    float a = fmaxf(hv[j],0.f);
    l0 = fmaf(a, Wc2[2*j],   l0);
    l1 = fmaf(a, Wc2[2*j+1], l1);
  }
  out[2LL*n]=l0; out[2LL*n+1]=l1;
}

static inline size_t al256(size_t x){ return (x+255)&~(size_t)255; }

extern "C" void kernel_launch(void* const* d_in, const int* in_sizes, int n_in,
                              void* d_out, int out_size, void* d_ws, size_t ws_size,
                              hipStream_t stream){
  const float* x_seq=(const float*)d_in[0];
  const int*   ei   =(const int*)d_in[1];
  const float* ew   =(const float*)d_in[2];
  const float* W0=(const float*)d_in[3];  const float* b0=(const float*)d_in[4];
  const float* g0=(const float*)d_in[5];  const float* be0=(const float*)d_in[6];
  const float* W1=(const float*)d_in[7];  const float* b1=(const float*)d_in[8];
  const float* g1=(const float*)d_in[9];  const float* be1=(const float*)d_in[10];
  const float* Wih=(const float*)d_in[11];const float* Whh=(const float*)d_in[12];
  const float* bih=(const float*)d_in[13];const float* bhh=(const float*)d_in[14];
  const float* Wc1=(const float*)d_in[15];const float* bc1=(const float*)d_in[16];
  const float* Wc2=(const float*)d_in[17];const float* bc2=(const float*)d_in[18];
  float* outp=(float*)d_out;

  char* p=(char*)d_ws; size_t off=0;
  auto alloc=[&](size_t bytes)->void*{ void* r=p+off; off=al256(off+bytes); return r; };
  float* deg    =(float*)alloc((size_t)NN*4);
  float* dis    =(float*)alloc((size_t)NN*4);
  int*   cnt    =(int*)  alloc((size_t)NN*4);
  int*   offs   =(int*)  alloc((size_t)(NN+1)*4);
  int*   cursor =(int*)  alloc((size_t)NN*4);
  int*   bsum   =(int*)  alloc((size_t)NB*4);
  int*   bpre   =(int*)  alloc((size_t)NB*4);
  int2*  csr    =(int2*) alloc((size_t)NE*8);
  float* WihT   =(float*)alloc((size_t)144*48*4);
  float* WhhT   =(float*)alloc((size_t)144*48*4);
  float* z0     =(float*)alloc((size_t)NN*HID*4);
  float* z1     =(float*)alloc((size_t)NN*HID*4);
  unsigned* A   =(unsigned*)alloc((size_t)NN*576 + 1024);   // bf16 [n][f][t6], 576B/row
  float* h1     =(float*)alloc((size_t)NN*TT*HID*4);
  float* h2     =(float*)alloc((size_t)NN*TT*HID*4);

  const int GN=(NN+255)/256, GE=(NE+255)/256;
  const int GMM=(NN*4+255)/256;          // 4 threads/node
  const int GAGG=(NN*64+255)/256;        // 1 wave/node

  k_setup  <<<GN,256,0,stream>>>(deg,cnt,Wih,Whh,WihT,WhhT);
  k_degcnt <<<GE,256,0,stream>>>(ei,ew,deg,cnt);
  k_partA  <<<NB,256,0,stream>>>(cnt,deg,dis,bsum);
  k_midB   <<<1,256,0,stream>>>(bsum,bpre,offs);
  k_offsC  <<<NB,256,0,stream>>>(cnt,bpre,offs,cursor);
  k_scatter<<<GE,256,0,stream>>>(ei,ew,dis,cursor,csr);
  hipMemsetAsync(z0,0,(size_t)NN*HID*4,stream);

  // layer 0
  k_mm0<<<GMM,256,0,stream>>>(x_seq, W0, A);
  k_agg<<<GAGG,256,0,stream>>>(A,b0,g0,be0,nullptr,h1,offs,csr,dis);
  // layer 1 (residual = h1)
  k_mm1<<<GMM,256,0,stream>>>(h1, W1, A);
  k_agg<<<GAGG,256,0,stream>>>(A,b1,g1,be1,h1,h2,offs,csr,dis);
  // GRU over time
  for(int t=0;t<TT;t++){
    const float* hin=(t&1)? z1:z0;
    float* hout=(t&1)? z0:z1;
    k_gru<<<dim3(GN,3),256,0,stream>>>(h2+(long long)t*HID, (long long)TT*HID, WihT,WhhT,bih,bhh,hin,hout);
  }
  // after t=5 (odd), final hidden is in z0
  k_cls<<<GN,256,0,stream>>>(z0,Wc1,bc1,Wc2,bc2,outp);
}